// Round 2
// baseline (695.397 us; speedup 1.0000x reference)
//
#include <hip/hip_runtime.h>
#include <math.h>

typedef unsigned short u16;
typedef unsigned int u32;
typedef __attribute__((ext_vector_type(8))) short short8;   // 8 bf16 (4 VGPRs)
typedef __attribute__((ext_vector_type(4))) float f32x4;

#define DIM 384
#define HID 1536

static __device__ __forceinline__ float bf2f(u32 b){ return __uint_as_float(b << 16); }
static __device__ __forceinline__ u16 f2bf(float f){
  u32 u = __float_as_uint(f);
  u32 r = (u + 0x7fffu + ((u >> 16) & 1u)) >> 16;
  return (u16)r;
}
// tanh-form GELU via sigmoid; |err| ~1e-4 in our operating range
static __device__ __forceinline__ float gelu_fast(float v){
  float u = v * fmaf(0.0713548162726f, v * v, 1.59576912161f);
  float e = __builtin_amdgcn_exp2f(-1.44269504089f * u);
  return v * __builtin_amdgcn_rcpf(1.0f + e);
}
// async global->LDS, 16B/lane; LDS dest = wave-uniform base + lane*16
static __device__ __forceinline__ void gload_lds16(const u16* g, u16* l){
  __builtin_amdgcn_global_load_lds(
      (__attribute__((address_space(1))) void*)(void*)const_cast<u16*>(g),
      (__attribute__((address_space(3))) void*)(void*)l, 16, 0, 0);
}

// ---------------- LayerNorm: f32 in, bf16 out ------------------------------
__global__ __launch_bounds__(256) void ln_kernel(const float* __restrict__ x,
    const float* __restrict__ sc, const float* __restrict__ bi, u16* __restrict__ y){
  int lane = threadIdx.x & 63;
  int row = blockIdx.x * 4 + (threadIdx.x >> 6);
  const float* xr = x + (size_t)row * DIM;
  float v[6];
  float s = 0.f, sq = 0.f;
#pragma unroll
  for (int i = 0; i < 6; ++i){
    float f = xr[lane + 64*i];
    v[i] = f; s += f; sq += f*f;
  }
#pragma unroll
  for (int o = 1; o < 64; o <<= 1){ s += __shfl_xor(s, o); sq += __shfl_xor(sq, o); }
  float mean = s * (1.0f/DIM);
  float var = sq * (1.0f/DIM) - mean*mean;
  float inv = rsqrtf(var + 1e-5f);
  u16* yr = y + (size_t)row * DIM;
#pragma unroll
  for (int i = 0; i < 6; ++i){
    int c = lane + 64*i;
    yr[c] = f2bf((v[i] - mean) * inv * sc[c] + bi[c]);
  }
}

// ---------------- 3D RoPE, in-place on q (bf16) ----------------------------
__global__ __launch_bounds__(256) void rope_kernel(u16* __restrict__ q,
    const int* __restrict__ Tp, const int* __restrict__ Hp, const int* __restrict__ Wp,
    int Mtok){
  int idx = blockIdx.x * 256 + threadIdx.x;   // one thread per rotated pair
  int tok = idx / 192;                         // 192 pairs per token
  if (tok >= Mtok) return;
  int p = idx - tok * 192;
  int H = *Hp, W = *Wp, T = *Tp;
  int HW = H * W;
  int Ns = T * HW;
  int n = tok % Ns;
  int head = p / 12;
  int pp = p - head * 12;
  int s = pp >> 2, f = pp & 3;
  float pos;
  if (s == 0)      pos = (float)(n / HW);
  else if (s == 1) pos = (float)((n / W) % H);
  else             pos = (float)(n % W);
  const float LOG2_10000 = 13.28771237954945f;
  float inv = __builtin_amdgcn_exp2f(-0.25f * (float)f * LOG2_10000);
  float ang = pos * inv;
  float sn = __sinf(ang), cs = __cosf(ang);
  size_t base = (size_t)tok * DIM + head * 24 + s * 8 + 2 * f;
  u32 u = *(u32*)(q + base);
  float x1 = bf2f(u & 0xffffu), x2 = bf2f(u >> 16);
  float y1 = x1 * cs - x2 * sn;
  float y2 = x1 * sn + x2 * cs;
  *(u32*)(q + base) = (u32)f2bf(y1) | ((u32)f2bf(y2) << 16);
}

// -------- weight transpose+convert: f32 in[R][C] -> bf16 out[C][R'] --------
template<int R, int C>
__global__ __launch_bounds__(256) void transpose_kernel(
    const float* __restrict__ s0, const float* __restrict__ s1,
    const float* __restrict__ s2, const float* __restrict__ s3,
    u16* __restrict__ d0, u16* __restrict__ d1, u16* __restrict__ d2, u16* __restrict__ d3,
    int dstStride){
  const float* src = (blockIdx.z == 0) ? s0 : (blockIdx.z == 1) ? s1 : (blockIdx.z == 2) ? s2 : s3;
  u16* dst         = (blockIdx.z == 0) ? d0 : (blockIdx.z == 1) ? d1 : (blockIdx.z == 2) ? d2 : d3;
  __shared__ u16 t[32][33];
  int tx = threadIdx.x & 31, ty = threadIdx.x >> 5;  // 32 x 8
  int r0 = blockIdx.y * 32, c0 = blockIdx.x * 32;
#pragma unroll
  for (int i = 0; i < 4; ++i)
    t[ty + 8*i][tx] = f2bf(src[(size_t)(r0 + ty + 8*i) * C + c0 + tx]);
  __syncthreads();
#pragma unroll
  for (int i = 0; i < 4; ++i)
    dst[(size_t)(c0 + ty + 8*i) * dstStride + r0 + tx] = t[tx][ty + 8*i];
}

// ---------------- sum 3 bias vectors of 384 --------------------------------
__global__ void bias3_kernel(const float* __restrict__ b, float* __restrict__ o){
  int n = threadIdx.x;
  o[n] = b[n] + b[384 + n] + b[768 + n];
}

// ---------------- MFMA GEMM: C = A[M,K] @ Bt[N,K]^T ------------------------
enum { E_NONE = 0, E_BIAS = 1, E_RES_F32 = 3, E_ATOMIC = 6 };

template<int BM, int N, int K, int EPI>
__global__ __launch_bounds__(256) void gemm_kernel(
    const u16* __restrict__ A, const u16* __restrict__ Bt,
    void* __restrict__ Cv, const float* __restrict__ bias,
    const float* __restrict__ res, float* __restrict__ accbuf){
  constexpr int BN = 128, BK = 64;
  constexpr int MT = BM / 32, NT = 4;
  constexpr int AIT = BM / 32, BIT = 4;
  __shared__ __align__(16) u16 As[BM * BK];
  __shared__ __align__(16) u16 Bs[BN * BK];
  const int tid = threadIdx.x;
  const int lane = tid & 63;
  const int wv = tid >> 6;
  const int wm = (wv >> 1) * (BM / 2);
  const int wn = (wv & 1) * 64;
  const int quad = lane >> 4;
  const int l16 = lane & 15;
  const int rsw = l16 & 7;
  const size_t m0 = (size_t)blockIdx.x * BM;
  const int n0 = blockIdx.y * BN;
  const int srow = lane >> 3;
  const int scol = ((lane & 7) ^ srow) * 8;

  f32x4 acc[MT][NT];
  const f32x4 zero = {0.f, 0.f, 0.f, 0.f};
#pragma unroll
  for (int mt = 0; mt < MT; ++mt)
#pragma unroll
    for (int nt = 0; nt < NT; ++nt) acc[mt][nt] = zero;

  for (int kt = 0; kt < K; kt += BK){
#pragma unroll
    for (int i = 0; i < AIT; ++i){
      int seg = i * 4 + wv;
      gload_lds16(A + (m0 + (size_t)(seg * 8 + srow)) * K + kt + scol, As + seg * 512);
    }
#pragma unroll
    for (int i = 0; i < BIT; ++i){
      int seg = i * 4 + wv;
      gload_lds16(Bt + (size_t)(n0 + seg * 8 + srow) * K + kt + scol, Bs + seg * 512);
    }
    __syncthreads();
#pragma unroll
    for (int kk = 0; kk < 2; ++kk){
      short8 af[MT], bfr[NT];
#pragma unroll
      for (int mt = 0; mt < MT; ++mt)
        af[mt] = *(const short8*)(As + (wm + mt*16 + l16) * BK + (((kk*4 + quad) ^ rsw) << 3));
#pragma unroll
      for (int nt = 0; nt < NT; ++nt)
        bfr[nt] = *(const short8*)(Bs + (wn + nt*16 + l16) * BK + (((kk*4 + quad) ^ rsw) << 3));
#pragma unroll
      for (int mt = 0; mt < MT; ++mt)
#pragma unroll
        for (int nt = 0; nt < NT; ++nt)
          acc[mt][nt] = __builtin_amdgcn_mfma_f32_16x16x32_bf16(af[mt], bfr[nt], acc[mt][nt], 0, 0, 0);
    }
    __syncthreads();
  }

  // epilogue: C/D mapping col = lane&15, row = quad*4 + reg  [m89-verified]
#pragma unroll
  for (int mt = 0; mt < MT; ++mt){
#pragma unroll
    for (int nt = 0; nt < NT; ++nt){
      int ncol = n0 + wn + nt*16 + l16;
      float bv = (EPI != E_NONE) ? bias[ncol] : 0.f;
      size_t mbase = m0 + wm + mt*16 + quad*4;
#pragma unroll
      for (int r = 0; r < 4; ++r){
        size_t off = (mbase + r) * N + ncol;
        float vv = acc[mt][nt][r];
        if      (EPI == E_NONE)      ((u16*)Cv)[off] = f2bf(vv);
        else if (EPI == E_BIAS)      ((u16*)Cv)[off] = f2bf(vv + bv);
        else /* E_RES_F32 */         accbuf[off] = vv + bv + res[off];
      }
    }
  }
}

// ---------------- Fused MLP v2: C = gelu(A @ W1t^T + b1) @ W2t^T (+b2) -----
// Key insight: each wave consumes a DISJOINT slice of W1 (64 hid rows) and
// W2 (48 out rows) -> LDS-staging weights has zero cross-wave reuse. So W1/W2
// fragments are loaded DIRECTLY global->registers (16B/lane = 16 full 64B
// lines per instr, L2-resident weights). LDS holds only A (staged once,
// 48 KB) + H chunk (32 KB) = 80 KB -> 2 blocks/CU, and only 2 barriers per
// hid-chunk (protecting the Hs write).
// SPLIT=1: grid.y=2 halves hid; partial C atomicAdd'd (f32) into outp, with
// XCD-bijective remap so each XCD half caches only its 3.5 MB weight slice.
template<int HIDT, int CHUNKS, int SPLIT, int EPI>
__global__ __launch_bounds__(512, 4) void fused_mlp2_kernel(
    const u16* __restrict__ A, const u16* __restrict__ W1t, const u16* __restrict__ W2t,
    const float* __restrict__ b1, const float* __restrict__ b2, void* __restrict__ outp){
  __shared__ __align__(16) u16 As[6 * 64 * 64];   // 48 KB: A[64][384], 6 k-tiles
  __shared__ __align__(16) u16 Hs[4 * 64 * 64];   // 32 KB: H chunk, 4 k-panels

  int bx, hb;
  if (SPLIT){
    int lin = blockIdx.x + (int)gridDim.x * blockIdx.y;   // 0..511
    int xcd = lin & 7, idx = lin >> 3;
    bx = (xcd & 3) * 64 + idx;          // 0..255
    hb = (xcd >> 2) * (CHUNKS * 256);   // hid half per XCD group
  } else { bx = blockIdx.x; hb = 0; }

  const int tid  = threadIdx.x;
  const int lane = tid & 63;
  const int wv   = tid >> 6;          // 0..7
  const int quad = lane >> 4;
  const int l16  = lane & 15;
  const int rsw  = l16 & 7;
  const size_t m0 = (size_t)bx * 64;
  const int srow = lane >> 3;
  const int scol = ((lane & 7) ^ srow) * 8;
  const int uwm = (wv & 1) * 32;      // up-phase: H row half
  const int pan = wv >> 1;            // up-phase: H col panel (64 wide)
  const int dwn = wv * 48;            // down-phase: C col slice

  // stage A[64][384] once (6 k-tiles x 8 row-segs, pre-swizzled source)
#pragma unroll
  for (int i = 0; i < 6; ++i){
    int lin2 = i * 8 + wv;            // tile=i, seg=wv
    gload_lds16(A + (m0 + (size_t)(wv * 8 + srow)) * 384 + i * 64 + scol, As + lin2 * 512);
  }
  __syncthreads();

  f32x4 cacc[4][3];
  const f32x4 zero = {0.f, 0.f, 0.f, 0.f};
#pragma unroll
  for (int mt = 0; mt < 4; ++mt)
#pragma unroll
    for (int nt = 0; nt < 3; ++nt) cacc[mt][nt] = zero;

  for (int c = 0; c < CHUNKS; ++c){
    const int hc = hb + c * 256;
    // ---- up: H[64][256] = A @ W1t[hc..hc+256][384]^T (W1 direct to regs) --
    f32x4 hacc[2][4];
#pragma unroll
    for (int mt = 0; mt < 2; ++mt)
#pragma unroll
      for (int nt = 0; nt < 4; ++nt) hacc[mt][nt] = zero;

    for (int kt = 0; kt < 6; ++kt){
#pragma unroll
      for (int kk = 0; kk < 2; ++kk){
        short8 af[2], bfr[4];
#pragma unroll
        for (int mt = 0; mt < 2; ++mt)
          af[mt] = *(const short8*)(As + kt*4096 + (uwm + mt*16 + l16)*64 + (((kk*4 + quad) ^ rsw) << 3));
#pragma unroll
        for (int nt = 0; nt < 4; ++nt)
          bfr[nt] = *(const short8*)(W1t + (size_t)(hc + pan*64 + nt*16 + l16) * 384 + kt*64 + (kk*4 + quad)*8);
#pragma unroll
        for (int mt = 0; mt < 2; ++mt)
#pragma unroll
          for (int nt = 0; nt < 4; ++nt)
            hacc[mt][nt] = __builtin_amdgcn_mfma_f32_16x16x32_bf16(af[mt], bfr[nt], hacc[mt][nt], 0, 0, 0);
      }
    }

    // ---- gelu + bf16 -> Hs (swizzled to match down-phase af reads) --------
    __syncthreads();   // all waves done reading Hs of previous chunk
#pragma unroll
    for (int nt = 0; nt < 4; ++nt){
      int pc = nt*16 + l16;
      float bv = b1[hc + pan*64 + pc];
      u16* hp = Hs + pan*4096;
#pragma unroll
      for (int mt = 0; mt < 2; ++mt){
#pragma unroll
        for (int r = 0; r < 4; ++r){
          int row = uwm + mt*16 + quad*4 + r;
          hp[row*64 + (((pc >> 3) ^ (row & 7)) << 3) + (pc & 7)] = f2bf(gelu_fast(hacc[mt][nt][r] + bv));
        }
      }
    }
    __syncthreads();

    // ---- down: C += H @ W2t[:, hc..hc+256]^T (W2 direct to regs) ----------
#pragma unroll
    for (int q = 0; q < 4; ++q){
#pragma unroll
      for (int kk = 0; kk < 2; ++kk){
        short8 af[4], bfr[3];
#pragma unroll
        for (int mt = 0; mt < 4; ++mt)
          af[mt] = *(const short8*)(Hs + q*4096 + (mt*16 + l16)*64 + (((kk*4 + quad) ^ rsw) << 3));
#pragma unroll
        for (int nt = 0; nt < 3; ++nt)
          bfr[nt] = *(const short8*)(W2t + (size_t)(dwn + nt*16 + l16) * HIDT + hc + q*64 + (kk*4 + quad)*8);
#pragma unroll
        for (int mt = 0; mt < 4; ++mt)
#pragma unroll
          for (int nt = 0; nt < 3; ++nt)
            cacc[mt][nt] = __builtin_amdgcn_mfma_f32_16x16x32_bf16(af[mt], bfr[nt], cacc[mt][nt], 0, 0, 0);
      }
    }
  }

  // ---- epilogue: C/D mapping col = lane&15, row = quad*4 + reg ------------
#pragma unroll
  for (int nt = 0; nt < 3; ++nt){
    int col = dwn + nt*16 + l16;
    float bv = (SPLIT && hb != 0) ? 0.f : b2[col];   // bias added exactly once
#pragma unroll
    for (int mt = 0; mt < 4; ++mt){
      size_t mbase = m0 + mt*16 + quad*4;
#pragma unroll
      for (int r = 0; r < 4; ++r){
        size_t off = (mbase + r) * DIM + col;
        float vv = cacc[mt][nt][r] + bv;
        if (EPI == E_BIAS) ((u16*)outp)[off] = f2bf(vv);
        else /* E_ATOMIC */ unsafeAtomicAdd((float*)outp + off, vv);
      }
    }
  }
}

extern "C" void kernel_launch(void* const* d_in, const int* in_sizes, int n_in,
                              void* d_out, int out_size, void* d_ws, size_t ws_size,
                              hipStream_t stream) {
  const int W11 = DIM * HID;   // 589824
  const float* x   = (const float*)d_in[0];
  const float* n1s = (const float*)d_in[1];
  const float* n1b = (const float*)d_in[2];
  const float* n2s = (const float*)d_in[3];
  const float* n2b = (const float*)d_in[4];
  const float* qw  = (const float*)d_in[5];
  const float* tw1 = (const float*)d_in[6] + 4 * W11;  // titan_w1[4]
  const float* tb1 = (const float*)d_in[7] + 4 * HID;  // titan_b1[4]
  const float* tw2 = (const float*)d_in[8] + 4 * W11;  // titan_w2[4]
  const float* tb2 = (const float*)d_in[9] + 4 * DIM;  // titan_b2[4]
  const float* ow  = (const float*)d_in[10];
  const float* ob  = (const float*)d_in[11];
  const float* cw1 = (const float*)d_in[12];
  const float* cb1 = (const float*)d_in[13];
  const float* cw2 = (const float*)d_in[14];
  const float* cb2 = (const float*)d_in[15];
  const int* Tp = (const int*)d_in[16];
  const int* Hp = (const int*)d_in[17];
  const int* Wp = (const int*)d_in[18];
  const int M = in_sizes[0] / DIM;   // 16384 tokens

  char* ws = (char*)d_ws;
  if (ws_size < 22611456u) return;
  u16*  y    = (u16*) (ws + 0);            // M x 384 bf16 (LN out, then t1, then LN2 out)
  u16*  qwT  = (u16*) (ws + 12582912);     // 384 x 384
  u16*  owT  = (u16*) (ws + 12877824);     // 384 x 384
  u16*  w1T  = (u16*) (ws + 13172736);     // 1536 x 384
  u16*  w2T  = (u16*) (ws + 14352384);     // 384 x 1536
  u16*  cw1T = (u16*) (ws + 15532032);     // 4608 x 384 (3 stacked)
  u16*  cw2T = (u16*) (ws + 19070976);     // 384 x 4608 (K-stacked)
  float* cb2s = (float*)(ws + 22609920);   // 384 f32
  u16*  qb   = (u16*)d_out;                // bf16 q scratch; later f32 x2/out

  // 1. transpose+convert weights to bf16 [N][K]
  transpose_kernel<384,384><<<dim3(12,12,2),256,0,stream>>>(
      qw, ow, qw, qw, qwT, owT, qwT, qwT, 384);
  transpose_kernel<384,1536><<<dim3(48,12,4),256,0,stream>>>(
      tw1, cw1, cw1 + W11, cw1 + 2*W11, w1T, cw1T, cw1T + W11, cw1T + 2*W11, 384);
  transpose_kernel<1536,384><<<dim3(12,48,1),256,0,stream>>>(
      tw2, tw2, tw2, tw2, w2T, w2T, w2T, w2T, 1536);
  transpose_kernel<1536,384><<<dim3(12,48,3),256,0,stream>>>(
      cw2, cw2 + W11, cw2 + 2*W11, cw2, cw2T, cw2T + 1536, cw2T + 3072, cw2T, 4608);
  bias3_kernel<<<1,384,0,stream>>>(cb2, cb2s);

  // 2. y = LN1(x)
  ln_kernel<<<M/4,256,0,stream>>>(x, n1s, n1b, y);
  // 3. q = y @ q_w   (bf16, into d_out)
  gemm_kernel<64,384,384,E_NONE><<<dim3(M/64,3),256,0,stream>>>(y, qwT, qb, nullptr, nullptr, nullptr);
  // 4. RoPE(q) in-place
  rope_kernel<<<(M*192)/256,256,0,stream>>>(qb, Tp, Hp, Wp, M);
  // 5+6. t1 = gelu(q @ w1 + b1) @ w2 + b2   (fused, q in d_out -> t1 in y)
  fused_mlp2_kernel<1536,6,0,E_BIAS><<<dim3(M/64,1),512,0,stream>>>(
      qb, w1T, w2T, tb1, tb2, y);
  // 7. x2 = x + t1 @ out_w + out_b   (f32, into d_out)
  gemm_kernel<64,384,384,E_RES_F32><<<dim3(M/64,3),256,0,stream>>>(
      y, owT, nullptr, ob, x, (float*)d_out);
  // 8. y2 = LN2(x2)
  ln_kernel<<<M/4,256,0,stream>>>((const float*)d_out, n2s, n2b, y);
  // 9. cms MLPs: d_out += gelu(y @ cw1cat + cb1) @ cw2cat + cb2s (hid-split x2)
  fused_mlp2_kernel<4608,9,1,E_ATOMIC><<<dim3(M/64,2),512,0,stream>>>(
      y, cw1T, cw2T, cb1, cb2s, d_out);
}

// Round 3
// 436.872 us; speedup vs baseline: 1.5918x; 1.5918x over previous
//
#include <hip/hip_runtime.h>
#include <math.h>

typedef unsigned short u16;
typedef unsigned int u32;
typedef __attribute__((ext_vector_type(8))) short short8;   // 8 bf16 (4 VGPRs)
typedef __attribute__((ext_vector_type(4))) float f32x4;

#define DIM 384
#define HID 1536

static __device__ __forceinline__ float bf2f(u32 b){ return __uint_as_float(b << 16); }
static __device__ __forceinline__ u16 f2bf(float f){
  u32 u = __float_as_uint(f);
  u32 r = (u + 0x7fffu + ((u >> 16) & 1u)) >> 16;
  return (u16)r;
}
// tanh-form GELU via sigmoid; |err| ~1e-4 in our operating range
static __device__ __forceinline__ float gelu_fast(float v){
  float u = v * fmaf(0.0713548162726f, v * v, 1.59576912161f);
  float e = __builtin_amdgcn_exp2f(-1.44269504089f * u);
  return v * __builtin_amdgcn_rcpf(1.0f + e);
}
// async global->LDS, 16B/lane; LDS dest = wave-uniform base + lane*16
static __device__ __forceinline__ void gload_lds16(const u16* g, u16* l){
  __builtin_amdgcn_global_load_lds(
      (__attribute__((address_space(1))) void*)(void*)const_cast<u16*>(g),
      (__attribute__((address_space(3))) void*)(void*)l, 16, 0, 0);
}
// counted vmcnt wait (T4: never drain to 0 in the main loop)
template<int N> static __device__ __forceinline__ void vm_wait(){
  if constexpr (N == 0)      asm volatile("s_waitcnt vmcnt(0)" ::: "memory");
  else if constexpr (N == 5) asm volatile("s_waitcnt vmcnt(5)" ::: "memory");
  else if constexpr (N == 6) asm volatile("s_waitcnt vmcnt(6)" ::: "memory");
  else                       asm volatile("s_waitcnt vmcnt(0)" ::: "memory");
}
static __device__ __forceinline__ void barrier_raw(){
  asm volatile("s_barrier" ::: "memory");
}
static __device__ __forceinline__ void lgkm_wait0(){
  asm volatile("s_waitcnt lgkmcnt(0)" ::: "memory");
}

// ---------------- LayerNorm: f32 in, bf16 out ------------------------------
__global__ __launch_bounds__(256) void ln_kernel(const float* __restrict__ x,
    const float* __restrict__ sc, const float* __restrict__ bi, u16* __restrict__ y){
  int lane = threadIdx.x & 63;
  int row = blockIdx.x * 4 + (threadIdx.x >> 6);
  const float* xr = x + (size_t)row * DIM;
  float v[6];
  float s = 0.f, sq = 0.f;
#pragma unroll
  for (int i = 0; i < 6; ++i){
    float f = xr[lane + 64*i];
    v[i] = f; s += f; sq += f*f;
  }
#pragma unroll
  for (int o = 1; o < 64; o <<= 1){ s += __shfl_xor(s, o); sq += __shfl_xor(sq, o); }
  float mean = s * (1.0f/DIM);
  float var = sq * (1.0f/DIM) - mean*mean;
  float inv = rsqrtf(var + 1e-5f);
  u16* yr = y + (size_t)row * DIM;
#pragma unroll
  for (int i = 0; i < 6; ++i){
    int c = lane + 64*i;
    yr[c] = f2bf((v[i] - mean) * inv * sc[c] + bi[c]);
  }
}

// ---------------- 3D RoPE, in-place on q (bf16) ----------------------------
__global__ __launch_bounds__(256) void rope_kernel(u16* __restrict__ q,
    const int* __restrict__ Tp, const int* __restrict__ Hp, const int* __restrict__ Wp,
    int Mtok){
  int idx = blockIdx.x * 256 + threadIdx.x;   // one thread per rotated pair
  int tok = idx / 192;                         // 192 pairs per token
  if (tok >= Mtok) return;
  int p = idx - tok * 192;
  int H = *Hp, W = *Wp, T = *Tp;
  int HW = H * W;
  int Ns = T * HW;
  int n = tok % Ns;
  int head = p / 12;
  int pp = p - head * 12;
  int s = pp >> 2, f = pp & 3;
  float pos;
  if (s == 0)      pos = (float)(n / HW);
  else if (s == 1) pos = (float)((n / W) % H);
  else             pos = (float)(n % W);
  const float LOG2_10000 = 13.28771237954945f;
  float inv = __builtin_amdgcn_exp2f(-0.25f * (float)f * LOG2_10000);
  float ang = pos * inv;
  float sn = __sinf(ang), cs = __cosf(ang);
  size_t base = (size_t)tok * DIM + head * 24 + s * 8 + 2 * f;
  u32 u = *(u32*)(q + base);
  float x1 = bf2f(u & 0xffffu), x2 = bf2f(u >> 16);
  float y1 = x1 * cs - x2 * sn;
  float y2 = x1 * sn + x2 * cs;
  *(u32*)(q + base) = (u32)f2bf(y1) | ((u32)f2bf(y2) << 16);
}

// -------- weight transpose+convert: f32 in[R][C] -> bf16 out[C][R'] --------
template<int R, int C>
__global__ __launch_bounds__(256) void transpose_kernel(
    const float* __restrict__ s0, const float* __restrict__ s1,
    const float* __restrict__ s2, const float* __restrict__ s3,
    u16* __restrict__ d0, u16* __restrict__ d1, u16* __restrict__ d2, u16* __restrict__ d3,
    int dstStride){
  const float* src = (blockIdx.z == 0) ? s0 : (blockIdx.z == 1) ? s1 : (blockIdx.z == 2) ? s2 : s3;
  u16* dst         = (blockIdx.z == 0) ? d0 : (blockIdx.z == 1) ? d1 : (blockIdx.z == 2) ? d2 : d3;
  __shared__ u16 t[32][33];
  int tx = threadIdx.x & 31, ty = threadIdx.x >> 5;  // 32 x 8
  int r0 = blockIdx.y * 32, c0 = blockIdx.x * 32;
#pragma unroll
  for (int i = 0; i < 4; ++i)
    t[ty + 8*i][tx] = f2bf(src[(size_t)(r0 + ty + 8*i) * C + c0 + tx]);
  __syncthreads();
#pragma unroll
  for (int i = 0; i < 4; ++i)
    dst[(size_t)(c0 + ty + 8*i) * dstStride + r0 + tx] = t[tx][ty + 8*i];
}

// ---------------- sum 3 bias vectors of 384 --------------------------------
__global__ void bias3_kernel(const float* __restrict__ b, float* __restrict__ o){
  int n = threadIdx.x;
  o[n] = b[n] + b[384 + n] + b[768 + n];
}

// ---------------- MFMA GEMM: C = A[M,K] @ Bt[N,K]^T ------------------------
enum { E_NONE = 0, E_BIAS = 1, E_RES_F32 = 3, E_FINAL = 5 };

template<int BM, int N, int K, int EPI>
__global__ __launch_bounds__(256) void gemm_kernel(
    const u16* __restrict__ A, const u16* __restrict__ Bt,
    void* __restrict__ Cv, const float* __restrict__ bias,
    const float* __restrict__ res, float* __restrict__ accbuf){
  constexpr int BN = 128, BK = 64;
  constexpr int MT = BM / 32, NT = 4;
  constexpr int AIT = BM / 32, BIT = 4;
  __shared__ __align__(16) u16 As[BM * BK];
  __shared__ __align__(16) u16 Bs[BN * BK];
  const int tid = threadIdx.x;
  const int lane = tid & 63;
  const int wv = tid >> 6;
  const int wm = (wv >> 1) * (BM / 2);
  const int wn = (wv & 1) * 64;
  const int quad = lane >> 4;
  const int l16 = lane & 15;
  const int rsw = l16 & 7;
  const size_t m0 = (size_t)blockIdx.x * BM;
  const int n0 = blockIdx.y * BN;
  const int srow = lane >> 3;
  const int scol = ((lane & 7) ^ srow) * 8;

  f32x4 acc[MT][NT];
  const f32x4 zero = {0.f, 0.f, 0.f, 0.f};
#pragma unroll
  for (int mt = 0; mt < MT; ++mt)
#pragma unroll
    for (int nt = 0; nt < NT; ++nt) acc[mt][nt] = zero;

  for (int kt = 0; kt < K; kt += BK){
#pragma unroll
    for (int i = 0; i < AIT; ++i){
      int seg = i * 4 + wv;
      gload_lds16(A + (m0 + (size_t)(seg * 8 + srow)) * K + kt + scol, As + seg * 512);
    }
#pragma unroll
    for (int i = 0; i < BIT; ++i){
      int seg = i * 4 + wv;
      gload_lds16(Bt + (size_t)(n0 + seg * 8 + srow) * K + kt + scol, Bs + seg * 512);
    }
    __syncthreads();
#pragma unroll
    for (int kk = 0; kk < 2; ++kk){
      short8 af[MT], bfr[NT];
#pragma unroll
      for (int mt = 0; mt < MT; ++mt)
        af[mt] = *(const short8*)(As + (wm + mt*16 + l16) * BK + (((kk*4 + quad) ^ rsw) << 3));
#pragma unroll
      for (int nt = 0; nt < NT; ++nt)
        bfr[nt] = *(const short8*)(Bs + (wn + nt*16 + l16) * BK + (((kk*4 + quad) ^ rsw) << 3));
#pragma unroll
      for (int mt = 0; mt < MT; ++mt)
#pragma unroll
        for (int nt = 0; nt < NT; ++nt)
          acc[mt][nt] = __builtin_amdgcn_mfma_f32_16x16x32_bf16(af[mt], bfr[nt], acc[mt][nt], 0, 0, 0);
    }
    __syncthreads();
  }

  // epilogue: C/D mapping col = lane&15, row = quad*4 + reg  [m89-verified]
#pragma unroll
  for (int mt = 0; mt < MT; ++mt){
#pragma unroll
    for (int nt = 0; nt < NT; ++nt){
      int ncol = n0 + wn + nt*16 + l16;
      float bv = (EPI != E_NONE) ? bias[ncol] : 0.f;
      size_t mbase = m0 + wm + mt*16 + quad*4;
#pragma unroll
      for (int r = 0; r < 4; ++r){
        size_t off = (mbase + r) * N + ncol;
        float vv = acc[mt][nt][r];
        if      (EPI == E_NONE)      ((u16*)Cv)[off] = f2bf(vv);
        else if (EPI == E_BIAS)      ((u16*)Cv)[off] = f2bf(vv + bv);
        else /* E_RES_F32 */         accbuf[off] = vv + bv + res[off];
      }
    }
  }
}

// ---------------- Fused MLP v3: C = gelu(A @ W1t^T + b1) @ W2t^T (+b2) -----
// Round-1's verified address math, re-scheduled as a pipelined 2-buffer ring
// (T3+T4): each tile = {issue NEXT tile's gload_lds into other buffer;
// s_waitcnt vmcnt(N) with N = next tile's load count (never 0 mid-loop);
// s_barrier; compute; s_barrier}. Loads stay in flight across barriers, so
// every stage has a full tile of compute to hide its L2 latency (round 1
// exposed it fully: load->syncthreads(vmcnt0 drain)->compute).
// LDS: ring 2x48 KB + Hs 32 KB = 128 KB, 1 block/CU, 8 waves.
// Per chunk (BH=256): 6 up-tiles (A|W1 fused panel, 5 loads/thread) ->
// gelu->Hs -> 4 down-tiles (W2 [384][64], 6 loads/thread).
template<int HIDT, int NCH, int EPI>
__global__ __launch_bounds__(512, 2) void fused_mlp3_kernel(
    const u16* __restrict__ A, const u16* __restrict__ W1t, const u16* __restrict__ W2t,
    const float* __restrict__ b1, const float* __restrict__ b2,
    const float* __restrict__ accbuf, void* __restrict__ outp){
  __shared__ __align__(16) u16 ring[2][384 * 64];  // 2 x 48 KB staging
  __shared__ __align__(16) u16 Hs[4 * 64 * 64];    // 32 KB H chunk, 4 k-panels

  const int tid  = threadIdx.x;
  const int lane = tid & 63;
  const int wv   = tid >> 6;          // 0..7
  const int quad = lane >> 4;
  const int l16  = lane & 15;
  const int rsw  = l16 & 7;
  const size_t m0 = (size_t)blockIdx.x * 64;
  const int srow = lane >> 3;
  const int scol = ((lane & 7) ^ srow) * 8;
  const int uwm = (wv & 1) * 32;      // up-phase: H row half
  const int pan = wv >> 1;            // up-phase: H col panel (64 wide)
  const int dwn = wv * 48;            // down-phase: C col slice

  // up-tile stage: rows 0..63 = A k-tile, rows 64..319 = W1 panel k-tile
  auto stage_up = [&](int hc, int kt, u16* buf){
#pragma unroll
    for (int i = 0; i < 5; ++i){
      int seg = i * 8 + wv;
      const u16* src = (i == 0)
          ? A + (m0 + (size_t)(wv * 8 + srow)) * 384 + kt * 64 + scol
          : W1t + ((size_t)hc + (seg - 8) * 8 + srow) * 384 + kt * 64 + scol;
      gload_lds16(src, buf + seg * 512);
    }
  };
  // down-tile stage: rows 0..383 = W2 out-rows, k-slice q
  auto stage_dn = [&](int hc, int q, u16* buf){
#pragma unroll
    for (int i = 0; i < 6; ++i){
      int seg = i * 8 + wv;
      gload_lds16(W2t + (size_t)(seg * 8 + srow) * HIDT + hc + q * 64 + scol,
                  buf + seg * 512);
    }
  };

  f32x4 cacc[4][3];
  const f32x4 zero = {0.f, 0.f, 0.f, 0.f};
#pragma unroll
  for (int mt = 0; mt < 4; ++mt)
#pragma unroll
    for (int nt = 0; nt < 3; ++nt) cacc[mt][nt] = zero;

  stage_up(0, 0, ring[0]);   // prologue: U0 -> buf0 (5 loads in flight)

  for (int c = 0; c < NCH; ++c){
    const int hc = c * 256;
    f32x4 hacc[2][4];
#pragma unroll
    for (int mt = 0; mt < 2; ++mt)
#pragma unroll
      for (int nt = 0; nt < 4; ++nt) hacc[mt][nt] = zero;

    // ---- up: H[64][256] = A @ W1t[hc..hc+256]^T, pipelined k-tiles -------
#pragma unroll
    for (int kt = 0; kt < 6; ++kt){
      if (kt < 5){ stage_up(hc, kt + 1, ring[(kt + 1) & 1]); vm_wait<5>(); }
      else       { stage_dn(hc, 0, ring[0]);                 vm_wait<6>(); }
      barrier_raw();
      const u16* buf = ring[kt & 1];
#pragma unroll
      for (int kk = 0; kk < 2; ++kk){
        short8 af[2], bfr[4];
#pragma unroll
        for (int mt = 0; mt < 2; ++mt)
          af[mt] = *(const short8*)(buf + (uwm + mt*16 + l16) * 64 + (((kk*4 + quad) ^ rsw) << 3));
#pragma unroll
        for (int nt = 0; nt < 4; ++nt)
          bfr[nt] = *(const short8*)(buf + (64 + pan*64 + nt*16 + l16) * 64 + (((kk*4 + quad) ^ rsw) << 3));
#pragma unroll
        for (int mt = 0; mt < 2; ++mt)
#pragma unroll
          for (int nt = 0; nt < 4; ++nt)
            hacc[mt][nt] = __builtin_amdgcn_mfma_f32_16x16x32_bf16(af[mt], bfr[nt], hacc[mt][nt], 0, 0, 0);
      }
      barrier_raw();
    }

    // ---- gelu + bf16 -> Hs (swizzled to match down-phase af reads) -------
#pragma unroll
    for (int nt = 0; nt < 4; ++nt){
      int pc = nt*16 + l16;
      float bv = b1[hc + pan*64 + pc];
      u16* hp = Hs + pan*4096;
#pragma unroll
      for (int mt = 0; mt < 2; ++mt){
#pragma unroll
        for (int r = 0; r < 4; ++r){
          int row = uwm + mt*16 + quad*4 + r;
          hp[row*64 + (((pc >> 3) ^ (row & 7)) << 3) + (pc & 7)] = f2bf(gelu_fast(hacc[mt][nt][r] + bv));
        }
      }
    }
    lgkm_wait0();
    barrier_raw();

    // ---- down: C += H @ W2t[:, hc..hc+256]^T, pipelined k-quarters -------
#pragma unroll
    for (int dt = 0; dt < 4; ++dt){
      if (dt < 3)            { stage_dn(hc, dt + 1, ring[(dt + 1) & 1]); vm_wait<6>(); }
      else if (c + 1 < NCH)  { stage_up(hc + 256, 0, ring[0]);           vm_wait<5>(); }
      else                   { vm_wait<0>(); }
      barrier_raw();
      const u16* buf = ring[dt & 1];
#pragma unroll
      for (int kk = 0; kk < 2; ++kk){
        short8 af[4], bfr[3];
#pragma unroll
        for (int mt = 0; mt < 4; ++mt)
          af[mt] = *(const short8*)(Hs + dt*4096 + (mt*16 + l16) * 64 + (((kk*4 + quad) ^ rsw) << 3));
#pragma unroll
        for (int nt = 0; nt < 3; ++nt)
          bfr[nt] = *(const short8*)(buf + (dwn + nt*16 + l16) * 64 + (((kk*4 + quad) ^ rsw) << 3));
#pragma unroll
        for (int mt = 0; mt < 4; ++mt)
#pragma unroll
          for (int nt = 0; nt < 3; ++nt)
            cacc[mt][nt] = __builtin_amdgcn_mfma_f32_16x16x32_bf16(af[mt], bfr[nt], cacc[mt][nt], 0, 0, 0);
      }
      barrier_raw();
    }
  }

  // ---- epilogue: C/D mapping col = lane&15, row = quad*4 + reg ------------
#pragma unroll
  for (int nt = 0; nt < 3; ++nt){
    int col = dwn + nt*16 + l16;
    float bv = b2[col];
#pragma unroll
    for (int mt = 0; mt < 4; ++mt){
      size_t mbase = m0 + mt*16 + quad*4;
#pragma unroll
      for (int r = 0; r < 4; ++r){
        size_t off = (mbase + r) * DIM + col;
        float vv = cacc[mt][nt][r] + bv;
        if (EPI == E_BIAS) ((u16*)outp)[off] = f2bf(vv);
        else /* E_FINAL */ ((float*)outp)[off] = accbuf[off] + vv;
      }
    }
  }
}

extern "C" void kernel_launch(void* const* d_in, const int* in_sizes, int n_in,
                              void* d_out, int out_size, void* d_ws, size_t ws_size,
                              hipStream_t stream) {
  const int W11 = DIM * HID;   // 589824
  const float* x   = (const float*)d_in[0];
  const float* n1s = (const float*)d_in[1];
  const float* n1b = (const float*)d_in[2];
  const float* n2s = (const float*)d_in[3];
  const float* n2b = (const float*)d_in[4];
  const float* qw  = (const float*)d_in[5];
  const float* tw1 = (const float*)d_in[6] + 4 * W11;  // titan_w1[4]
  const float* tb1 = (const float*)d_in[7] + 4 * HID;  // titan_b1[4]
  const float* tw2 = (const float*)d_in[8] + 4 * W11;  // titan_w2[4]
  const float* tb2 = (const float*)d_in[9] + 4 * DIM;  // titan_b2[4]
  const float* ow  = (const float*)d_in[10];
  const float* ob  = (const float*)d_in[11];
  const float* cw1 = (const float*)d_in[12];
  const float* cb1 = (const float*)d_in[13];
  const float* cw2 = (const float*)d_in[14];
  const float* cb2 = (const float*)d_in[15];
  const int* Tp = (const int*)d_in[16];
  const int* Hp = (const int*)d_in[17];
  const int* Wp = (const int*)d_in[18];
  const int M = in_sizes[0] / DIM;   // 16384 tokens

  char* ws = (char*)d_ws;
  if (ws_size < 22611456u) return;
  u16*  y    = (u16*) (ws + 0);            // M x 384 bf16 (LN out, then t1, then LN2 out)
  u16*  qwT  = (u16*) (ws + 12582912);     // 384 x 384
  u16*  owT  = (u16*) (ws + 12877824);     // 384 x 384
  u16*  w1T  = (u16*) (ws + 13172736);     // 1536 x 384
  u16*  w2T  = (u16*) (ws + 14352384);     // 384 x 1536
  u16*  cw1T = (u16*) (ws + 15532032);     // 4608 x 384 (3 stacked)
  u16*  cw2T = (u16*) (ws + 19070976);     // 384 x 4608 (K-stacked)
  float* cb2s = (float*)(ws + 22609920);   // 384 f32
  u16*  qb   = (u16*)d_out;                // bf16 q scratch; later f32 x2/out

  // 1. transpose+convert weights to bf16 [N][K]
  transpose_kernel<384,384><<<dim3(12,12,2),256,0,stream>>>(
      qw, ow, qw, qw, qwT, owT, qwT, qwT, 384);
  transpose_kernel<384,1536><<<dim3(48,12,4),256,0,stream>>>(
      tw1, cw1, cw1 + W11, cw1 + 2*W11, w1T, cw1T, cw1T + W11, cw1T + 2*W11, 384);
  transpose_kernel<1536,384><<<dim3(12,48,1),256,0,stream>>>(
      tw2, tw2, tw2, tw2, w2T, w2T, w2T, w2T, 1536);
  transpose_kernel<1536,384><<<dim3(12,48,3),256,0,stream>>>(
      cw2, cw2 + W11, cw2 + 2*W11, cw2, cw2T, cw2T + 1536, cw2T + 3072, cw2T, 4608);
  bias3_kernel<<<1,384,0,stream>>>(cb2, cb2s);

  // 2. y = LN1(x)
  ln_kernel<<<M/4,256,0,stream>>>(x, n1s, n1b, y);
  // 3. q = y @ q_w   (bf16, into d_out)
  gemm_kernel<64,384,384,E_NONE><<<dim3(M/64,3),256,0,stream>>>(y, qwT, qb, nullptr, nullptr, nullptr);
  // 4. RoPE(q) in-place
  rope_kernel<<<(M*192)/256,256,0,stream>>>(qb, Tp, Hp, Wp, M);
  // 5+6. t1 = gelu(q @ w1 + b1) @ w2 + b2   (fused, q in d_out -> t1 in y)
  fused_mlp3_kernel<1536,6,E_BIAS><<<M/64,512,0,stream>>>(
      qb, w1T, w2T, tb1, tb2, nullptr, y);
  // 7. x2 = x + t1 @ out_w + out_b   (f32, into d_out)
  gemm_kernel<64,384,384,E_RES_F32><<<dim3(M/64,3),256,0,stream>>>(
      y, owT, nullptr, ob, x, (float*)d_out);
  // 8. y2 = LN2(x2)
  ln_kernel<<<M/4,256,0,stream>>>((const float*)d_out, n2s, n2b, y);
  // 9. cms: d_out = x2 + gelu(y @ cw1cat + cb1) @ cw2cat + cb2s   (one pass)
  fused_mlp3_kernel<4608,18,E_FINAL><<<M/64,512,0,stream>>>(
      y, cw1T, cw2T, cb1, cb2s, (const float*)d_out, d_out);
}